// Round 1
// 71.478 us; speedup vs baseline: 1.0304x; 1.0304x over previous
//
#include <hip/hip_runtime.h>

#define BB 4
#define IN_DIM 8
#define OUT_DIM 64
#define N_WIN 64
#define N_SEQ 4096
#define N_REAL 6144
#define TT 64                      // t-tile per block (two 32-wide MFMA columns)
#define NTB (N_REAL / TT)          // 96 t-tiles per batch
#define NROW 127                   // valid window rows: tau in [t0-63, t0+63]

typedef __attribute__((ext_vector_type(8)))  short short8;
typedef __attribute__((ext_vector_type(16))) float floatx16;

static __device__ __forceinline__ unsigned short f2bf(float f) {
    union { float f; unsigned int u; } v; v.f = f;
    unsigned int r = v.u + 0x7fffu + ((v.u >> 16) & 1u);   // round-nearest-even
    return (unsigned short)(r >> 16);
}

// ---- K1: pack weights w[o][i][l] -> w2[l][o][i] (bf16), COALESCED loads
//          (lanes sweep l => 8 contiguous 256-B segments per wave; 16-B scatter
//          stores are fire-and-forget) + all 384 window lower-bounds in parallel.
__global__ __launch_bounds__(64)
void k_prep(const float* __restrict__ w, const int* __restrict__ sidx,
            unsigned short* __restrict__ w2, int* __restrict__ lob)
{
    const int tg = blockIdx.x * 64 + threadIdx.x;   // 0..4095, 64 blocks on 64 CUs
    const int l = tg & 63, o = tg >> 6;             // lane = l -> coalesced loads
    const float* wp = w + (size_t)o * (IN_DIM * N_WIN) + l;
    unsigned short v[8];
    #pragma unroll
    for (int i = 0; i < 8; ++i) v[i] = f2bf(wp[(size_t)i * N_WIN]);
    uint4 pk;
    pk.x = v[0] | ((unsigned)v[1] << 16); pk.y = v[2] | ((unsigned)v[3] << 16);
    pk.z = v[4] | ((unsigned)v[5] << 16); pk.w = v[6] | ((unsigned)v[7] << 16);
    *(uint4*)(w2 + ((size_t)(l * OUT_DIM + o)) * 8) = pk;

    if (tg < BB * NTB) {                            // one thread per (b, t-tile)
        const int b  = tg / NTB, bx = tg - b * NTB;
        const int vlo = bx * TT - 63;
        const int* idxb = sidx + b * N_SEQ;
        int lo = 0, hi = N_SEQ;
        while (lo < hi) { int m = (lo + hi) >> 1; if (idxb[m] < vlo) lo = m + 1; else hi = m; }
        lob[tg] = lo;
    }
}

// ---- K2: MFMA GEMM, 64 t x 64 o per block, 4 waves (2 o-halves x 2 t-columns).
//          One 127-row scatter window + one w2 stream feeds both t-columns.
__global__ __launch_bounds__(256)
void k_gemm(const float* __restrict__ x, const unsigned short* __restrict__ w2,
            const float* __restrict__ bias, const int* __restrict__ sidx,
            const int* __restrict__ lob, float* __restrict__ out)
{
    __shared__ unsigned short zlds[128 * 8];        // rows tau = t0-63 .. t0+63 (2 KB)

    const int tid = threadIdx.x;
    const int bx  = blockIdx.x;                     // 0..95
    const int b   = blockIdx.y;
    const int t0  = bx * TT;
    const int vlo = t0 - 63;
    const int lo  = lob[b * NTB + bx];              // uniform -> scalar load

    // zero the LDS tile (512 dwords)
    unsigned int* zw = (unsigned int*)zlds;
    zw[tid] = 0u; zw[tid + 256] = 0u;

    // issue scatter-source loads NOW (coalesced; latency overlaps zero+barrier)
    const int ig = tid >> 5;                        // input channel 0..7
    const int sl = tid & 31;                        // source slot lane
    const int* idxb = sidx + b * N_SEQ;
    const float* xb = x + ((size_t)b * IN_DIM + ig) * N_SEQ;
    int   rarr[4]; float xv[4];
    #pragma unroll
    for (int c = 0; c < 4; ++c) {                   // 4 x 32 slots cover <=127 sources
        int s = lo + c * 32 + sl;
        bool valid = (s < N_SEQ);
        rarr[c] = valid ? (idxb[s] - vlo) : -1;
        xv[c]   = valid ? xb[s] : 0.f;
    }

    // A-fragment prefetch (no LDS dependency); th-twin waves share addresses (L1)
    const int ln = tid & 31;                        // t / o lane coordinate
    const int lq = (tid >> 5) & 1;                  // k-half within wave
    const int mh = (tid >> 6) & 1;                  // which 32-o half
    const int th = tid >> 7;                        // which 32-t column
    const short8* wv = (const short8*)w2;
    short8 apre[8];
    #pragma unroll
    for (int k = 0; k < 8; ++k)
        apre[k] = wv[(2 * k + lq) * OUT_DIM + mh * 32 + ln];

    __syncthreads();                                // zeros complete
    #pragma unroll
    for (int c = 0; c < 4; ++c)
        if ((unsigned)rarr[c] < (unsigned)NROW)
            zlds[rarr[c] * 8 + ig] = f2bf(xv[c]);
    __syncthreads();                                // scatter complete

    floatx16 acc = {};
    const short8* zv = (const short8*)zlds;
    const int rbase = ln + th * 32 + 63;
    #pragma unroll
    for (int ks = 0; ks < 32; ++ks) {
        const int l = 2 * ks + lq;                  // lag for this k-half
        short8 a  = (ks < 8) ? apre[ks]
                             : wv[l * OUT_DIM + mh * 32 + ln];   // L1/L2-hot
        short8 bz = zv[rbase - l];                  // LDS b128, conflict-free
        acc = __builtin_amdgcn_mfma_f32_32x32x16_bf16(a, bz, acc, 0, 0, 0);
    }

    // C/D layout (m74/m101): col=lane&31 -> t, row=(p&3)+8*(p>>2)+4*(lane>>5) -> o
    #pragma unroll
    for (int p = 0; p < 16; ++p) {
        int o = (p & 3) + 8 * (p >> 2) + 4 * lq + mh * 32;
        out[((size_t)b * OUT_DIM + o) * N_REAL + t0 + th * 32 + ln] = acc[p] + bias[o];
    }
}

extern "C" void kernel_launch(void* const* d_in, const int* in_sizes, int n_in,
                              void* d_out, int out_size, void* d_ws, size_t ws_size,
                              hipStream_t stream) {
    const float* px = nullptr; const float* pw = nullptr;
    const float* pb = nullptr; const int* ps = nullptr;

    for (int i = 0; i < n_in; ++i) {
        switch (in_sizes[i]) {
            case BB * IN_DIM * N_SEQ:        px = (const float*)d_in[i]; break; // x
            case OUT_DIM * IN_DIM * N_WIN:   pw = (const float*)d_in[i]; break; // weight
            case OUT_DIM:                    pb = (const float*)d_in[i]; break; // bias
            case BB * N_SEQ:                 ps = (const int*)d_in[i];   break; // sourceIdx
            default: break;
        }
    }
    if (!px || !pw || !pb || !ps) {
        px = (const float*)d_in[0]; pw = (const float*)d_in[1];
        pb = (const float*)d_in[2]; ps = (const int*)d_in[3];
    }

    unsigned short* w2 = (unsigned short*)d_ws;                  // 64 KB
    int* lob = (int*)((char*)d_ws + 64 * 1024);                  // 1.5 KB
    float* out = (float*)d_out;

    k_prep<<<64, 64, 0, stream>>>(pw, ps, w2, lob);
    k_gemm<<<dim3(NTB, BB), 256, 0, stream>>>(px, w2, pb, ps, lob, out);
}